// Round 8
// baseline (180.615 us; speedup 1.0000x reference)
//
#include <hip/hip_runtime.h>

#define B        4
#define N        16384       // 2^14
#define NPOINT   2048        // 2^11
#define C        64
#define NSAMPLE  32
#define CH       (C + 3)     // 67 output channels
#define RADIUS2  0.01f
#define NCELL    1000        // 10^3 cells per batch (cell size = radius)
#define CSTRIDE  1032        // cell_start row stride (ints) >= NCELL+1
#define CAP      256         // per-query candidate cap (mean ~68, 22 sigma)

// Intra-wave LDS fence: drain this wave's DS ops, forbid compiler motion.
// All qg LDS state is per-wave. (Harness-verified rounds 1-2-4-5-6-7.)
#define WAVE_FENCE() asm volatile("s_waitcnt lgkmcnt(0)" ::: "memory")

__device__ __forceinline__ int clamp10(int v) {
    return v < 0 ? 0 : (v > 9 ? 9 : v);
}

__device__ __forceinline__ int cell_of(float x, float y, float z) {
    return (clamp10((int)(x * 10.f)) * 10 + clamp10((int)(y * 10.f))) * 10
         + clamp10((int)(z * 10.f));
}

// ---------------------------------------------------------------------------
// Zero the per-cell counters (ws is poisoned each call).
// ---------------------------------------------------------------------------
__global__ __launch_bounds__(256) void zero_kernel(int* __restrict__ p, int n) {
    const int i = blockIdx.x * 256 + threadIdx.x;
    if (i < n) p[i] = 0;
}

// ---------------------------------------------------------------------------
// 64x64 feature transpose tile body (256 threads).
// ---------------------------------------------------------------------------
__device__ __forceinline__ void transpose_body(const float* __restrict__ f,
                                               float* __restrict__ ft,
                                               int n0, int b, int t,
                                               float (*tile)[65]) {
    const int r16 = t >> 4;                  // 0..15
    const int x4  = t & 15;                  // 0..15
    #pragma unroll
    for (int it = 0; it < 4; ++it) {
        const int cc = it * 16 + r16;
        const float4 v = *(const float4*)(f + ((size_t)b * C + cc) * N + n0 + x4 * 4);
        tile[cc][x4 * 4 + 0] = v.x;
        tile[cc][x4 * 4 + 1] = v.y;
        tile[cc][x4 * 4 + 2] = v.z;
        tile[cc][x4 * 4 + 3] = v.w;
    }
    __syncthreads();
    #pragma unroll
    for (int it = 0; it < 4; ++it) {
        const int nn = it * 16 + r16;
        float4 v;
        v.x = tile[x4 * 4 + 0][nn];
        v.y = tile[x4 * 4 + 1][nn];
        v.z = tile[x4 * 4 + 2][nn];
        v.w = tile[x4 * 4 + 3][nn];
        *(float4*)(ft + ((size_t)b * N + n0 + nn) * C + x4 * 4) = v;
    }
}

// ---------------------------------------------------------------------------
// Fused prep (round-1 harness-verified): blocks [0,256) count points per
// cell; blocks [256,1280) transpose features (B,C,N) -> (B,N,C).
// ---------------------------------------------------------------------------
__global__ __launch_bounds__(256) void prep_kernel(const float* __restrict__ xyz,
                                                   int* __restrict__ cnt,
                                                   const float* __restrict__ f,
                                                   float* __restrict__ ft) {
    __shared__ float tile[64][65];
    if (blockIdx.x < (B * N / 256)) {
        const int g = blockIdx.x * 256 + threadIdx.x;
        const int b = g >> 14;
        const float x = xyz[g * 3 + 0], y = xyz[g * 3 + 1], z = xyz[g * 3 + 2];
        atomicAdd(&cnt[(b << 10) + cell_of(x, y, z)], 1);
    } else {
        const int bi = blockIdx.x - (B * N / 256);
        transpose_body(f, ft, (bi & 255) * 64, bi >> 8, threadIdx.x, tile);
    }
}

// Standalone transpose (fallback tiers). grid = (N/64, B), block = 256
__global__ __launch_bounds__(256) void feat_transpose_kernel(
    const float* __restrict__ f, float* __restrict__ ft) {
    __shared__ float tile[64][65];
    transpose_body(f, ft, blockIdx.x * 64, blockIdx.y, threadIdx.x, tile);
}

// ---------------------------------------------------------------------------
// Exclusive scan over 1000 cells/batch (round-0/1 harness-verified).
// grid = B, block = 1024. Writes cell_start[0..1000], re-inits cnt as cursor.
// ---------------------------------------------------------------------------
__global__ __launch_bounds__(1024) void prefix_kernel(int* __restrict__ cnt,
                                                      int* __restrict__ cs) {
    __shared__ int wsum[16];
    const int t = threadIdx.x, b = blockIdx.x;
    const int w = t >> 6, l = t & 63;
    const int v = (t < NCELL) ? cnt[(b << 10) + t] : 0;
    int inc = v;                                   // wave-inclusive scan
    #pragma unroll
    for (int off = 1; off < 64; off <<= 1) {
        const int u = __shfl_up(inc, off);
        if (l >= off) inc += u;
    }
    if (l == 63) wsum[w] = inc;
    __syncthreads();
    if (t < 16) {                                  // scan the 16 wave sums
        int s = wsum[t];
        #pragma unroll
        for (int off = 1; off < 16; off <<= 1) {
            const int u = __shfl_up(s, off, 16);
            if (t >= off) s += u;
        }
        wsum[t] = s;
    }
    __syncthreads();
    const int base = (w > 0) ? wsum[w - 1] : 0;
    const int excl = base + inc - v;               // exclusive prefix
    if (t <= NCELL) cs[b * CSTRIDE + t] = excl;    // t==1000 -> total
    if (t < NCELL)  cnt[(b << 10) + t] = excl;     // cursor init
}

// ---------------------------------------------------------------------------
// Scatter points into cell-sorted array as float4(x,y,z,bitcast(index)).
// ---------------------------------------------------------------------------
__global__ __launch_bounds__(256) void scatter_kernel(const float* __restrict__ xyz,
                                                      int* __restrict__ cursor,
                                                      float4* __restrict__ sp) {
    const int g = blockIdx.x * 256 + threadIdx.x;
    const int b = g >> 14;
    const int n = g & (N - 1);
    const float x = xyz[g * 3 + 0], y = xyz[g * 3 + 1], z = xyz[g * 3 + 2];
    const int pos = atomicAdd(&cursor[(b << 10) + cell_of(x, y, z)], 1);
    sp[(b << 14) + pos] = make_float4(x, y, z, __int_as_float(n));
}

// ---------------------------------------------------------------------------
// QG v3 (round-7 harness-verified, 126.07 us config). IDEMPOTENT: reads only
// prep outputs, writes deterministic values to every output element. This
// round it is launched 3x as a TIMING PROBE: dur = base + 2*qg.
// ---------------------------------------------------------------------------
__global__ __launch_bounds__(256, 6) void qg_v3_kernel(
    const float*  __restrict__ xyz,      // (B,N,3)
    const float*  __restrict__ new_xyz,  // (B,NPOINT,3)
    const float*  __restrict__ ft,       // (B,N,C)
    const int*    __restrict__ cs,       // cell_start, CSTRIDE per batch
    const float4* __restrict__ sp,       // cell-sorted points
    float* __restrict__ out_cnt,         // B*NPOINT (cnt as float)
    float* __restrict__ out_feat)        // (B,CH,NPOINT,NSAMPLE)
{
    const int w = threadIdx.x >> 6;
    const int l = threadIdx.x & 63;
    const int q = blockIdx.x * 4 + w;
    const int b = q >> 11;
    const int j = q & (NPOINT - 1);

    __shared__ int cand_s[4][CAP];
    __shared__ int si_s[4][NSAMPLE];
    int* cand = cand_s[w];
    int* s_i  = si_s[w];

    const float qx = new_xyz[q * 3 + 0];
    const float qy = new_xyz[q * 3 + 1];
    const float qz = new_xyz[q * 3 + 2];

    const int cx = clamp10((int)(qx * 10.f));
    const int cy = clamp10((int)(qy * 10.f));
    const int cz = clamp10((int)(qz * 10.f));
    const int z0 = cz > 0 ? cz - 1 : 0;
    const int z1 = cz < 9 ? cz + 1 : 9;

    // prefetch all 9 run bounds in parallel (lanes 0..8), broadcast via shfl
    int sv = 0, ev = 0;
    if (l < 9) {
        const int xx = cx - 1 + l / 3;
        const int yy = cy - 1 + l % 3;
        if (xx >= 0 && xx <= 9 && yy >= 0 && yy <= 9) {
            const int cb = (xx * 10 + yy) * 10;
            sv = cs[b * CSTRIDE + cb + z0];
            ev = cs[b * CSTRIDE + cb + z1 + 1];
        }
    }

    const unsigned long long ltmask = (1ull << l) - 1ull;
    const float4* spb = sp + ((size_t)b << 14);

    // ---- 2-deep pipelined scan over the 9 runs ----
    int   rs_c = __shfl(sv, 0), re_c = __shfl(ev, 0);
    bool  a_n;
    float4 pt_n;
    {   // prefetch run 0, chunk 0 (clamped address: always a valid load)
        const int p  = rs_c + l;
        a_n = p < re_c;
        const int pc = a_n ? p : (re_c > rs_c ? re_c - 1 : 0);
        pt_n = spb[pc];
    }
    int total = 0, ncand = 0;
    for (int r = 0; r < 9; ++r) {
        const int rs = rs_c, re = re_c;
        const float4 pt = pt_n;
        const bool   act = a_n;
        if (r < 8) {        // issue NEXT run's first-chunk load immediately
            rs_c = __shfl(sv, r + 1);
            re_c = __shfl(ev, r + 1);
            const int p  = rs_c + l;
            a_n = p < re_c;
            const int pc = a_n ? p : (re_c > rs_c ? re_c - 1 : 0);
            pt_n = spb[pc];
        }
        // process current run's first chunk
        {
            const float dx = pt.x - qx, dy = pt.y - qy, dz = pt.z - qz;
            const float d2 = dx * dx + dy * dy + dz * dz;
            const bool in = act && (d2 < RADIUS2);
            const unsigned long long m = __ballot(in);
            if (in) {
                const int slot = ncand + __popcll(m & ltmask);
                if (slot < CAP) cand[slot] = __float_as_int(pt.w);
            }
            const int c = __popcll(m);
            total += c;
            ncand = ncand + c > CAP ? CAP : ncand + c;
        }
        // rare tail: current run longer than 64 points
        #pragma unroll 1
        for (int p0 = rs + 64; p0 < re; p0 += 64) {
            const int p = p0 + l;
            const bool tact = p < re;
            float4 tp = make_float4(1e9f, 1e9f, 1e9f, 0.f);
            if (tact) tp = spb[p];
            const float dx = tp.x - qx, dy = tp.y - qy, dz = tp.z - qz;
            const float d2 = dx * dx + dy * dy + dz * dz;
            const bool in = tact && (d2 < RADIUS2);
            const unsigned long long m = __ballot(in);
            if (in) {
                const int slot = ncand + __popcll(m & ltmask);
                if (slot < CAP) cand[slot] = __float_as_int(tp.w);
            }
            const int c = __popcll(m);
            total += c;
            ncand = ncand + c > CAP ? CAP : ncand + c;
        }
    }
    WAVE_FENCE();                        // cand[] appends visible wave-wide

    int cntv;
    if (total > CAP) {
        // overflow (astronomically unlikely, uniform data): ordered rescan
        const float* xb = xyz + (size_t)b * N * 3;
        int cnt2 = 0;
        for (int base = 0; base < N; base += 64) {
            const int p = base + l;
            const float dx = xb[p * 3 + 0] - qx;
            const float dy = xb[p * 3 + 1] - qy;
            const float dz = xb[p * 3 + 2] - qz;
            const float d2 = dx * dx + dy * dy + dz * dz;
            const bool in = d2 < RADIUS2;
            const unsigned long long m = __ballot(in);
            if (in) {
                const int slot = cnt2 + __popcll(m & ltmask);
                if (slot < NSAMPLE) s_i[slot] = p;
            }
            cnt2 += __popcll(m);
            if (cnt2 >= NSAMPLE) break;
        }
        cntv = cnt2 < NSAMPLE ? cnt2 : NSAMPLE;
    } else {
        // rank = #(smaller candidate indices) -> first NSAMPLE in index order
        const int K = ncand;             // == total
        for (int c = l; c < K; c += 64) {
            const int v = cand[c];
            int rnk = 0;
            for (int i = 0; i < K; ++i) rnk += (cand[i] < v) ? 1 : 0;
            if (rnk < NSAMPLE) s_i[rnk] = v;
        }
        cntv = total < NSAMPLE ? total : NSAMPLE;
    }
    WAVE_FENCE();                        // s_i writes visible

    if (l == 0) out_cnt[q] = (float)cntv;
    if (l < NSAMPLE && l >= cntv) s_i[l] = (cntv > 0) ? s_i[0] : 0;
    WAVE_FENCE();                        // fill writes visible

    // ---- xyz channels 0..2: 32 lanes, coalesced 128B per component ----
    const size_t plane = (size_t)NPOINT * NSAMPLE;          // 65536
    float* ob = out_feat + (size_t)b * CH * plane + (size_t)j * NSAMPLE;
    if (l < NSAMPLE) {
        const int i = s_i[l];
        const float* xp = xyz + ((size_t)b * N + i) * 3;
        ob[0 * plane + l] = xp[0] - qx;
        ob[1 * plane + l] = xp[1] - qy;
        ob[2 * plane + l] = xp[2] - qz;
    }

    // ---- feature channels 3..66: direct gather->store (round-6 verified) ----
    const float4* ft4 = (const float4*)ft;
    #pragma unroll
    for (int t = 0; t < 4; ++t) {
        const int k  = t * 8 + (l >> 3);
        const int c4 = l & 7;
        const int i  = s_i[k];
        const float4 va = ft4[((size_t)b * N + i) * (C / 4) + c4];
        const float4 vb = ft4[((size_t)b * N + i) * (C / 4) + 8 + c4];
        float* oa = ob + (size_t)(3 + c4 * 4) * plane + k;
        oa[0 * plane] = va.x;
        oa[1 * plane] = va.y;
        oa[2 * plane] = va.z;
        oa[3 * plane] = va.w;
        float* obp = ob + (size_t)(35 + c4 * 4) * plane + k;
        obp[0 * plane] = vb.x;
        obp[1 * plane] = vb.y;
        obp[2 * plane] = vb.z;
        obp[3 * plane] = vb.w;
    }
}

// ---------------------------------------------------------------------------
// Fallback tiers: linear-scan kernel (no grid, optional transposed features).
// ---------------------------------------------------------------------------
template <bool TRANSPOSED>
__global__ __launch_bounds__(64) void qg_wave_kernel(
    const float* __restrict__ xyz,
    const float* __restrict__ new_xyz,
    const float* __restrict__ feat,
    float* __restrict__ out_cnt,
    float* __restrict__ out_feat)
{
    const int q = blockIdx.x;
    const int b = q >> 11;
    const int j = q & (NPOINT - 1);
    const int l = threadIdx.x;

    __shared__ int   s_idx[NSAMPLE];
    __shared__ float s_tile[CH * 33];

    const float qx = new_xyz[q * 3 + 0];
    const float qy = new_xyz[q * 3 + 1];
    const float qz = new_xyz[q * 3 + 2];
    const float* xb = xyz + (size_t)b * N * 3;

    int cnt = 0;
    for (int base = 0; base < N; base += 64) {
        const int p = base + l;
        const float dx = xb[p * 3 + 0] - qx;
        const float dy = xb[p * 3 + 1] - qy;
        const float dz = xb[p * 3 + 2] - qz;
        const float d2 = dx * dx + dy * dy + dz * dz;
        const bool in = d2 < RADIUS2;
        const unsigned long long m = __ballot(in);
        if (in) {
            const int slot = cnt + __popcll(m & ((1ull << l) - 1ull));
            if (slot < NSAMPLE) s_idx[slot] = p;
        }
        cnt += __popcll(m);
        if (cnt >= NSAMPLE) break;
    }
    if (cnt > NSAMPLE) cnt = NSAMPLE;

    if (l == 0) out_cnt[q] = (float)cnt;
    __syncthreads();
    if (l < NSAMPLE && l >= cnt) s_idx[l] = (cnt > 0) ? s_idx[0] : 0;
    __syncthreads();

    #pragma unroll
    for (int p = 0; p < 8; ++p) {
        const int k  = p * 4 + (l >> 4);
        const int c4 = l & 15;
        const int i  = s_idx[k];
        if (TRANSPOSED) {
            const float4 v = ((const float4*)(feat + ((size_t)b * N + i) * C))[c4];
            const int ch = 3 + c4 * 4;
            s_tile[(ch + 0) * 33 + k] = v.x;
            s_tile[(ch + 1) * 33 + k] = v.y;
            s_tile[(ch + 2) * 33 + k] = v.z;
            s_tile[(ch + 3) * 33 + k] = v.w;
        } else {
            #pragma unroll
            for (int cc2 = 0; cc2 < 4; ++cc2) {
                const int c = c4 * 4 + cc2;
                s_tile[(3 + c) * 33 + k] = feat[((size_t)b * C + c) * N + i];
            }
        }
    }
    if (l < NSAMPLE) {
        const int i = s_idx[l];
        const float* xp = xyz + ((size_t)b * N + i) * 3;
        s_tile[0 * 33 + l] = xp[0] - qx;
        s_tile[1 * 33 + l] = xp[1] - qy;
        s_tile[2 * 33 + l] = xp[2] - qz;
    }
    __syncthreads();

    float4* of4 = (float4*)out_feat;
    for (int e4 = l; e4 < CH * 8; e4 += 64) {
        const int ch = e4 >> 3;
        const int k4 = e4 & 7;
        float4 v;
        v.x = s_tile[ch * 33 + k4 * 4 + 0];
        v.y = s_tile[ch * 33 + k4 * 4 + 1];
        v.z = s_tile[ch * 33 + k4 * 4 + 2];
        v.w = s_tile[ch * 33 + k4 * 4 + 3];
        of4[((size_t)(b * CH + ch) * NPOINT + j) * 8 + k4] = v;
    }
}

extern "C" void kernel_launch(void* const* d_in, const int* in_sizes, int n_in,
                              void* d_out, int out_size, void* d_ws, size_t ws_size,
                              hipStream_t stream) {
    const float* xyz      = (const float*)d_in[0];   // (B,N,3)
    const float* new_xyz  = (const float*)d_in[1];   // (B,NPOINT,3)
    const float* features = (const float*)d_in[2];   // (B,C,N)

    float* out_cnt  = (float*)d_out;                 // B*NPOINT
    float* out_feat = out_cnt + (size_t)B * NPOINT;  // (B,CH,NPOINT,NSAMPLE)

    char* ws = (char*)d_ws;
    const size_t ftB = (size_t)B * N * C * sizeof(float);     // 16 MB
    const size_t spB = (size_t)B * N * sizeof(float4);        // 4 MB
    const size_t csB = (size_t)B * CSTRIDE * sizeof(int);
    const size_t ccB = (size_t)B * 1024 * sizeof(int);
    const size_t need = ftB + spB + csB + ccB;

    if (ws_size >= need) {
        float*  ft = (float*)ws;
        float4* sp = (float4*)(ws + ftB);
        int*    cs = (int*)(ws + ftB + spB);
        int*    cc = (int*)(ws + ftB + spB + csB);
        zero_kernel<<<(B * 1024 + 255) / 256, 256, 0, stream>>>(cc, B * 1024);
        prep_kernel<<<(B * N / 256) + B * (N / 64), 256, 0, stream>>>(xyz, cc,
                                                                      features, ft);
        prefix_kernel<<<B, 1024, 0, stream>>>(cc, cs);
        scatter_kernel<<<B * N / 256, 256, 0, stream>>>(xyz, cc, sp);
        // TIMING PROBE: qg_v3 is idempotent; 3 launches => dur = base + 2*qg.
        qg_v3_kernel<<<B * NPOINT / 4, 256, 0, stream>>>(xyz, new_xyz, ft, cs, sp,
                                                         out_cnt, out_feat);
        qg_v3_kernel<<<B * NPOINT / 4, 256, 0, stream>>>(xyz, new_xyz, ft, cs, sp,
                                                         out_cnt, out_feat);
        qg_v3_kernel<<<B * NPOINT / 4, 256, 0, stream>>>(xyz, new_xyz, ft, cs, sp,
                                                         out_cnt, out_feat);
    } else if (ws_size >= ftB) {
        float* ft = (float*)ws;
        feat_transpose_kernel<<<dim3(N / 64, B), 256, 0, stream>>>(features, ft);
        qg_wave_kernel<true><<<B * NPOINT, 64, 0, stream>>>(xyz, new_xyz, ft,
                                                            out_cnt, out_feat);
    } else {
        qg_wave_kernel<false><<<B * NPOINT, 64, 0, stream>>>(xyz, new_xyz, features,
                                                             out_cnt, out_feat);
    }
}

// Round 9
// 125.179 us; speedup vs baseline: 1.4429x; 1.4429x over previous
//
#include <hip/hip_runtime.h>

#define B        4
#define N        16384       // 2^14
#define NPOINT   2048        // 2^11
#define C        64
#define NSAMPLE  32
#define CH       (C + 3)     // 67 output channels
#define RADIUS2  0.01f
#define NCELL    1000        // 10^3 cells per batch (cell size = radius)
#define CSTRIDE  1032        // cell_start row stride (ints) >= NCELL+1
#define CAP      256         // per-query candidate cap (mean ~68, 22 sigma)

// Intra-wave LDS fence: drain this wave's DS ops, forbid compiler motion.
// All qg LDS state is per-wave. (Harness-verified rounds 1-2-4-5-6-7-8.)
#define WAVE_FENCE() asm volatile("s_waitcnt lgkmcnt(0)" ::: "memory")

__device__ __forceinline__ int clamp10(int v) {
    return v < 0 ? 0 : (v > 9 ? 9 : v);
}

__device__ __forceinline__ int cell_of(float x, float y, float z) {
    return (clamp10((int)(x * 10.f)) * 10 + clamp10((int)(y * 10.f))) * 10
         + clamp10((int)(z * 10.f));
}

// ---------------------------------------------------------------------------
// Zero the per-cell counters (ws is poisoned each call).
// ---------------------------------------------------------------------------
__global__ __launch_bounds__(256) void zero_kernel(int* __restrict__ p, int n) {
    const int i = blockIdx.x * 256 + threadIdx.x;
    if (i < n) p[i] = 0;
}

// ---------------------------------------------------------------------------
// 64x64 feature transpose tile body (256 threads).
// ---------------------------------------------------------------------------
__device__ __forceinline__ void transpose_body(const float* __restrict__ f,
                                               float* __restrict__ ft,
                                               int n0, int b, int t,
                                               float (*tile)[65]) {
    const int r16 = t >> 4;                  // 0..15
    const int x4  = t & 15;                  // 0..15
    #pragma unroll
    for (int it = 0; it < 4; ++it) {
        const int cc = it * 16 + r16;
        const float4 v = *(const float4*)(f + ((size_t)b * C + cc) * N + n0 + x4 * 4);
        tile[cc][x4 * 4 + 0] = v.x;
        tile[cc][x4 * 4 + 1] = v.y;
        tile[cc][x4 * 4 + 2] = v.z;
        tile[cc][x4 * 4 + 3] = v.w;
    }
    __syncthreads();
    #pragma unroll
    for (int it = 0; it < 4; ++it) {
        const int nn = it * 16 + r16;
        float4 v;
        v.x = tile[x4 * 4 + 0][nn];
        v.y = tile[x4 * 4 + 1][nn];
        v.z = tile[x4 * 4 + 2][nn];
        v.w = tile[x4 * 4 + 3][nn];
        *(float4*)(ft + ((size_t)b * N + n0 + nn) * C + x4 * 4) = v;
    }
}

// ---------------------------------------------------------------------------
// Fused prep (round-1 harness-verified): blocks [0,256) count points per
// cell; blocks [256,1280) transpose features (B,C,N) -> (B,N,C).
// ---------------------------------------------------------------------------
__global__ __launch_bounds__(256) void prep_kernel(const float* __restrict__ xyz,
                                                   int* __restrict__ cnt,
                                                   const float* __restrict__ f,
                                                   float* __restrict__ ft) {
    __shared__ float tile[64][65];
    if (blockIdx.x < (B * N / 256)) {
        const int g = blockIdx.x * 256 + threadIdx.x;
        const int b = g >> 14;
        const float x = xyz[g * 3 + 0], y = xyz[g * 3 + 1], z = xyz[g * 3 + 2];
        atomicAdd(&cnt[(b << 10) + cell_of(x, y, z)], 1);
    } else {
        const int bi = blockIdx.x - (B * N / 256);
        transpose_body(f, ft, (bi & 255) * 64, bi >> 8, threadIdx.x, tile);
    }
}

// Standalone transpose (fallback tiers). grid = (N/64, B), block = 256
__global__ __launch_bounds__(256) void feat_transpose_kernel(
    const float* __restrict__ f, float* __restrict__ ft) {
    __shared__ float tile[64][65];
    transpose_body(f, ft, blockIdx.x * 64, blockIdx.y, threadIdx.x, tile);
}

// ---------------------------------------------------------------------------
// Exclusive scan over 1000 cells/batch (round-0/1 harness-verified).
// grid = B, block = 1024. Writes cell_start[0..1000], re-inits cnt as cursor.
// ---------------------------------------------------------------------------
__global__ __launch_bounds__(1024) void prefix_kernel(int* __restrict__ cnt,
                                                      int* __restrict__ cs) {
    __shared__ int wsum[16];
    const int t = threadIdx.x, b = blockIdx.x;
    const int w = t >> 6, l = t & 63;
    const int v = (t < NCELL) ? cnt[(b << 10) + t] : 0;
    int inc = v;                                   // wave-inclusive scan
    #pragma unroll
    for (int off = 1; off < 64; off <<= 1) {
        const int u = __shfl_up(inc, off);
        if (l >= off) inc += u;
    }
    if (l == 63) wsum[w] = inc;
    __syncthreads();
    if (t < 16) {                                  // scan the 16 wave sums
        int s = wsum[t];
        #pragma unroll
        for (int off = 1; off < 16; off <<= 1) {
            const int u = __shfl_up(s, off, 16);
            if (t >= off) s += u;
        }
        wsum[t] = s;
    }
    __syncthreads();
    const int base = (w > 0) ? wsum[w - 1] : 0;
    const int excl = base + inc - v;               // exclusive prefix
    if (t <= NCELL) cs[b * CSTRIDE + t] = excl;    // t==1000 -> total
    if (t < NCELL)  cnt[(b << 10) + t] = excl;     // cursor init
}

// ---------------------------------------------------------------------------
// Scatter points into cell-sorted array as float4(x,y,z,bitcast(index)).
// ---------------------------------------------------------------------------
__global__ __launch_bounds__(256) void scatter_kernel(const float* __restrict__ xyz,
                                                      int* __restrict__ cursor,
                                                      float4* __restrict__ sp) {
    const int g = blockIdx.x * 256 + threadIdx.x;
    const int b = g >> 14;
    const int n = g & (N - 1);
    const float x = xyz[g * 3 + 0], y = xyz[g * 3 + 1], z = xyz[g * 3 + 2];
    const int pos = atomicAdd(&cursor[(b << 10) + cell_of(x, y, z)], 1);
    sp[(b << 14) + pos] = make_float4(x, y, z, __int_as_float(n));
}

// ---------------------------------------------------------------------------
// QG v4 = round-7 verified qg_v3 + XCD-affinity block swizzle: blocks are
// remapped so XCD pair g services ONLY batch g/2 (blockIdx%8 -> XCD on
// MI355X round-robin dispatch). Each XCD's 4MB L2 then holds one batch's
// ft (4MB) + sp (256KB) working set instead of all four batches (17MB) ->
// gathers hit L2 instead of L3. Bijective remap; worst case neutral.
// ---------------------------------------------------------------------------
__global__ __launch_bounds__(256, 6) void qg_v4_kernel(
    const float*  __restrict__ xyz,      // (B,N,3)
    const float*  __restrict__ new_xyz,  // (B,NPOINT,3)
    const float*  __restrict__ ft,       // (B,N,C)
    const int*    __restrict__ cs,       // cell_start, CSTRIDE per batch
    const float4* __restrict__ sp,       // cell-sorted points
    float* __restrict__ out_cnt,         // B*NPOINT (cnt as float)
    float* __restrict__ out_feat)        // (B,CH,NPOINT,NSAMPLE)
{
    const int w = threadIdx.x >> 6;
    const int l = threadIdx.x & 63;
    // ---- XCD-affinity swizzle (grid = 2048 blocks, 8 XCDs, 4 batches) ----
    const int bid = blockIdx.x;
    const int xcd = bid & 7;                       // dispatch round-robin slot
    const int bb  = xcd >> 1;                      // batch for this XCD pair
    const int wi  = ((bid >> 3) << 1) + (xcd & 1); // 0..511 within batch
    const int q   = (bb << 11) + (wi << 2) + w;    // bijective over 8192
    const int b   = bb;
    const int j   = q & (NPOINT - 1);

    __shared__ int cand_s[4][CAP];
    __shared__ int si_s[4][NSAMPLE];
    int* cand = cand_s[w];
    int* s_i  = si_s[w];

    const float qx = new_xyz[q * 3 + 0];
    const float qy = new_xyz[q * 3 + 1];
    const float qz = new_xyz[q * 3 + 2];

    const int cx = clamp10((int)(qx * 10.f));
    const int cy = clamp10((int)(qy * 10.f));
    const int cz = clamp10((int)(qz * 10.f));
    const int z0 = cz > 0 ? cz - 1 : 0;
    const int z1 = cz < 9 ? cz + 1 : 9;

    // prefetch all 9 run bounds in parallel (lanes 0..8), broadcast via shfl
    int sv = 0, ev = 0;
    if (l < 9) {
        const int xx = cx - 1 + l / 3;
        const int yy = cy - 1 + l % 3;
        if (xx >= 0 && xx <= 9 && yy >= 0 && yy <= 9) {
            const int cb = (xx * 10 + yy) * 10;
            sv = cs[b * CSTRIDE + cb + z0];
            ev = cs[b * CSTRIDE + cb + z1 + 1];
        }
    }

    const unsigned long long ltmask = (1ull << l) - 1ull;
    const float4* spb = sp + ((size_t)b << 14);

    // ---- 2-deep pipelined scan over the 9 runs (round-7 verified) ----
    int   rs_c = __shfl(sv, 0), re_c = __shfl(ev, 0);
    bool  a_n;
    float4 pt_n;
    {   // prefetch run 0, chunk 0 (clamped address: always a valid load)
        const int p  = rs_c + l;
        a_n = p < re_c;
        const int pc = a_n ? p : (re_c > rs_c ? re_c - 1 : 0);
        pt_n = spb[pc];
    }
    int total = 0, ncand = 0;
    for (int r = 0; r < 9; ++r) {
        const int rs = rs_c, re = re_c;
        const float4 pt = pt_n;
        const bool   act = a_n;
        if (r < 8) {        // issue NEXT run's first-chunk load immediately
            rs_c = __shfl(sv, r + 1);
            re_c = __shfl(ev, r + 1);
            const int p  = rs_c + l;
            a_n = p < re_c;
            const int pc = a_n ? p : (re_c > rs_c ? re_c - 1 : 0);
            pt_n = spb[pc];
        }
        // process current run's first chunk
        {
            const float dx = pt.x - qx, dy = pt.y - qy, dz = pt.z - qz;
            const float d2 = dx * dx + dy * dy + dz * dz;
            const bool in = act && (d2 < RADIUS2);
            const unsigned long long m = __ballot(in);
            if (in) {
                const int slot = ncand + __popcll(m & ltmask);
                if (slot < CAP) cand[slot] = __float_as_int(pt.w);
            }
            const int c = __popcll(m);
            total += c;
            ncand = ncand + c > CAP ? CAP : ncand + c;
        }
        // rare tail: current run longer than 64 points
        #pragma unroll 1
        for (int p0 = rs + 64; p0 < re; p0 += 64) {
            const int p = p0 + l;
            const bool tact = p < re;
            float4 tp = make_float4(1e9f, 1e9f, 1e9f, 0.f);
            if (tact) tp = spb[p];
            const float dx = tp.x - qx, dy = tp.y - qy, dz = tp.z - qz;
            const float d2 = dx * dx + dy * dy + dz * dz;
            const bool in = tact && (d2 < RADIUS2);
            const unsigned long long m = __ballot(in);
            if (in) {
                const int slot = ncand + __popcll(m & ltmask);
                if (slot < CAP) cand[slot] = __float_as_int(tp.w);
            }
            const int c = __popcll(m);
            total += c;
            ncand = ncand + c > CAP ? CAP : ncand + c;
        }
    }
    WAVE_FENCE();                        // cand[] appends visible wave-wide

    int cntv;
    if (total > CAP) {
        // overflow (astronomically unlikely, uniform data): ordered rescan
        const float* xb = xyz + (size_t)b * N * 3;
        int cnt2 = 0;
        for (int base = 0; base < N; base += 64) {
            const int p = base + l;
            const float dx = xb[p * 3 + 0] - qx;
            const float dy = xb[p * 3 + 1] - qy;
            const float dz = xb[p * 3 + 2] - qz;
            const float d2 = dx * dx + dy * dy + dz * dz;
            const bool in = d2 < RADIUS2;
            const unsigned long long m = __ballot(in);
            if (in) {
                const int slot = cnt2 + __popcll(m & ltmask);
                if (slot < NSAMPLE) s_i[slot] = p;
            }
            cnt2 += __popcll(m);
            if (cnt2 >= NSAMPLE) break;
        }
        cntv = cnt2 < NSAMPLE ? cnt2 : NSAMPLE;
    } else {
        // rank = #(smaller candidate indices) -> first NSAMPLE in index order
        const int K = ncand;             // == total
        for (int c = l; c < K; c += 64) {
            const int v = cand[c];
            int rnk = 0;
            for (int i = 0; i < K; ++i) rnk += (cand[i] < v) ? 1 : 0;
            if (rnk < NSAMPLE) s_i[rnk] = v;
        }
        cntv = total < NSAMPLE ? total : NSAMPLE;
    }
    WAVE_FENCE();                        // s_i writes visible

    if (l == 0) out_cnt[q] = (float)cntv;
    if (l < NSAMPLE && l >= cntv) s_i[l] = (cntv > 0) ? s_i[0] : 0;
    WAVE_FENCE();                        // fill writes visible

    // ---- xyz channels 0..2: 32 lanes, coalesced 128B per component ----
    const size_t plane = (size_t)NPOINT * NSAMPLE;          // 65536
    float* ob = out_feat + (size_t)b * CH * plane + (size_t)j * NSAMPLE;
    if (l < NSAMPLE) {
        const int i = s_i[l];
        const float* xp = xyz + ((size_t)b * N + i) * 3;
        ob[0 * plane + l] = xp[0] - qx;
        ob[1 * plane + l] = xp[1] - qy;
        ob[2 * plane + l] = xp[2] - qz;
    }

    // ---- feature channels 3..66: direct gather->store (round-6 verified) ----
    const float4* ft4 = (const float4*)ft;
    #pragma unroll
    for (int t = 0; t < 4; ++t) {
        const int k  = t * 8 + (l >> 3);
        const int c4 = l & 7;
        const int i  = s_i[k];
        const float4 va = ft4[((size_t)b * N + i) * (C / 4) + c4];
        const float4 vb = ft4[((size_t)b * N + i) * (C / 4) + 8 + c4];
        float* oa = ob + (size_t)(3 + c4 * 4) * plane + k;
        oa[0 * plane] = va.x;
        oa[1 * plane] = va.y;
        oa[2 * plane] = va.z;
        oa[3 * plane] = va.w;
        float* obp = ob + (size_t)(35 + c4 * 4) * plane + k;
        obp[0 * plane] = vb.x;
        obp[1 * plane] = vb.y;
        obp[2 * plane] = vb.z;
        obp[3 * plane] = vb.w;
    }
}

// ---------------------------------------------------------------------------
// Fallback tiers: linear-scan kernel (no grid, optional transposed features).
// ---------------------------------------------------------------------------
template <bool TRANSPOSED>
__global__ __launch_bounds__(64) void qg_wave_kernel(
    const float* __restrict__ xyz,
    const float* __restrict__ new_xyz,
    const float* __restrict__ feat,
    float* __restrict__ out_cnt,
    float* __restrict__ out_feat)
{
    const int q = blockIdx.x;
    const int b = q >> 11;
    const int j = q & (NPOINT - 1);
    const int l = threadIdx.x;

    __shared__ int   s_idx[NSAMPLE];
    __shared__ float s_tile[CH * 33];

    const float qx = new_xyz[q * 3 + 0];
    const float qy = new_xyz[q * 3 + 1];
    const float qz = new_xyz[q * 3 + 2];
    const float* xb = xyz + (size_t)b * N * 3;

    int cnt = 0;
    for (int base = 0; base < N; base += 64) {
        const int p = base + l;
        const float dx = xb[p * 3 + 0] - qx;
        const float dy = xb[p * 3 + 1] - qy;
        const float dz = xb[p * 3 + 2] - qz;
        const float d2 = dx * dx + dy * dy + dz * dz;
        const bool in = d2 < RADIUS2;
        const unsigned long long m = __ballot(in);
        if (in) {
            const int slot = cnt + __popcll(m & ((1ull << l) - 1ull));
            if (slot < NSAMPLE) s_idx[slot] = p;
        }
        cnt += __popcll(m);
        if (cnt >= NSAMPLE) break;
    }
    if (cnt > NSAMPLE) cnt = NSAMPLE;

    if (l == 0) out_cnt[q] = (float)cnt;
    __syncthreads();
    if (l < NSAMPLE && l >= cnt) s_idx[l] = (cnt > 0) ? s_idx[0] : 0;
    __syncthreads();

    #pragma unroll
    for (int p = 0; p < 8; ++p) {
        const int k  = p * 4 + (l >> 4);
        const int c4 = l & 15;
        const int i  = s_idx[k];
        if (TRANSPOSED) {
            const float4 v = ((const float4*)(feat + ((size_t)b * N + i) * C))[c4];
            const int ch = 3 + c4 * 4;
            s_tile[(ch + 0) * 33 + k] = v.x;
            s_tile[(ch + 1) * 33 + k] = v.y;
            s_tile[(ch + 2) * 33 + k] = v.z;
            s_tile[(ch + 3) * 33 + k] = v.w;
        } else {
            #pragma unroll
            for (int cc2 = 0; cc2 < 4; ++cc2) {
                const int c = c4 * 4 + cc2;
                s_tile[(3 + c) * 33 + k] = feat[((size_t)b * C + c) * N + i];
            }
        }
    }
    if (l < NSAMPLE) {
        const int i = s_idx[l];
        const float* xp = xyz + ((size_t)b * N + i) * 3;
        s_tile[0 * 33 + l] = xp[0] - qx;
        s_tile[1 * 33 + l] = xp[1] - qy;
        s_tile[2 * 33 + l] = xp[2] - qz;
    }
    __syncthreads();

    float4* of4 = (float4*)out_feat;
    for (int e4 = l; e4 < CH * 8; e4 += 64) {
        const int ch = e4 >> 3;
        const int k4 = e4 & 7;
        float4 v;
        v.x = s_tile[ch * 33 + k4 * 4 + 0];
        v.y = s_tile[ch * 33 + k4 * 4 + 1];
        v.z = s_tile[ch * 33 + k4 * 4 + 2];
        v.w = s_tile[ch * 33 + k4 * 4 + 3];
        of4[((size_t)(b * CH + ch) * NPOINT + j) * 8 + k4] = v;
    }
}

extern "C" void kernel_launch(void* const* d_in, const int* in_sizes, int n_in,
                              void* d_out, int out_size, void* d_ws, size_t ws_size,
                              hipStream_t stream) {
    const float* xyz      = (const float*)d_in[0];   // (B,N,3)
    const float* new_xyz  = (const float*)d_in[1];   // (B,NPOINT,3)
    const float* features = (const float*)d_in[2];   // (B,C,N)

    float* out_cnt  = (float*)d_out;                 // B*NPOINT
    float* out_feat = out_cnt + (size_t)B * NPOINT;  // (B,CH,NPOINT,NSAMPLE)

    char* ws = (char*)d_ws;
    const size_t ftB = (size_t)B * N * C * sizeof(float);     // 16 MB
    const size_t spB = (size_t)B * N * sizeof(float4);        // 4 MB
    const size_t csB = (size_t)B * CSTRIDE * sizeof(int);
    const size_t ccB = (size_t)B * 1024 * sizeof(int);
    const size_t need = ftB + spB + csB + ccB;

    if (ws_size >= need) {
        float*  ft = (float*)ws;
        float4* sp = (float4*)(ws + ftB);
        int*    cs = (int*)(ws + ftB + spB);
        int*    cc = (int*)(ws + ftB + spB + csB);
        zero_kernel<<<(B * 1024 + 255) / 256, 256, 0, stream>>>(cc, B * 1024);
        prep_kernel<<<(B * N / 256) + B * (N / 64), 256, 0, stream>>>(xyz, cc,
                                                                      features, ft);
        prefix_kernel<<<B, 1024, 0, stream>>>(cc, cs);
        scatter_kernel<<<B * N / 256, 256, 0, stream>>>(xyz, cc, sp);
        qg_v4_kernel<<<B * NPOINT / 4, 256, 0, stream>>>(xyz, new_xyz, ft, cs, sp,
                                                         out_cnt, out_feat);
    } else if (ws_size >= ftB) {
        float* ft = (float*)ws;
        feat_transpose_kernel<<<dim3(N / 64, B), 256, 0, stream>>>(features, ft);
        qg_wave_kernel<true><<<B * NPOINT, 64, 0, stream>>>(xyz, new_xyz, ft,
                                                            out_cnt, out_feat);
    } else {
        qg_wave_kernel<false><<<B * NPOINT, 64, 0, stream>>>(xyz, new_xyz, features,
                                                             out_cnt, out_feat);
    }
}

// Round 10
// 124.785 us; speedup vs baseline: 1.4474x; 1.0032x over previous
//
#include <hip/hip_runtime.h>

#define B        4
#define N        16384       // 2^14
#define NPOINT   2048        // 2^11
#define C        64
#define NSAMPLE  32
#define CH       (C + 3)     // 67 output channels
#define RADIUS2  0.01f
#define NCELL    1000        // 10^3 cells per batch (cell size = radius)
#define CSTRIDE  1032        // cell_start row stride (ints) >= NCELL+1
#define CAP      256         // per-query candidate cap (mean ~68, 22 sigma)

// Intra-wave LDS fence: drain this wave's DS ops, forbid compiler motion.
// All qg LDS state is per-wave. (Harness-verified rounds 1-2-4-5-6-7-8-9.)
#define WAVE_FENCE() asm volatile("s_waitcnt lgkmcnt(0)" ::: "memory")

__device__ __forceinline__ int clamp10(int v) {
    return v < 0 ? 0 : (v > 9 ? 9 : v);
}

__device__ __forceinline__ int cell_of(float x, float y, float z) {
    return (clamp10((int)(x * 10.f)) * 10 + clamp10((int)(y * 10.f))) * 10
         + clamp10((int)(z * 10.f));
}

// ---------------------------------------------------------------------------
// 64x64 feature transpose tile body (256 threads).
// ---------------------------------------------------------------------------
__device__ __forceinline__ void transpose_body(const float* __restrict__ f,
                                               float* __restrict__ ft,
                                               int n0, int b, int t,
                                               float (*tile)[65]) {
    const int r16 = t >> 4;                  // 0..15
    const int x4  = t & 15;                  // 0..15
    #pragma unroll
    for (int it = 0; it < 4; ++it) {
        const int cc = it * 16 + r16;
        const float4 v = *(const float4*)(f + ((size_t)b * C + cc) * N + n0 + x4 * 4);
        tile[cc][x4 * 4 + 0] = v.x;
        tile[cc][x4 * 4 + 1] = v.y;
        tile[cc][x4 * 4 + 2] = v.z;
        tile[cc][x4 * 4 + 3] = v.w;
    }
    __syncthreads();
    #pragma unroll
    for (int it = 0; it < 4; ++it) {
        const int nn = it * 16 + r16;
        float4 v;
        v.x = tile[x4 * 4 + 0][nn];
        v.y = tile[x4 * 4 + 1][nn];
        v.z = tile[x4 * 4 + 2][nn];
        v.w = tile[x4 * 4 + 3][nn];
        *(float4*)(ft + ((size_t)b * N + n0 + nn) * C + x4 * 4) = v;
    }
}

// ---------------------------------------------------------------------------
// Fused prep (round-1 harness-verified): blocks [0,256) count points per
// cell; blocks [256,1280) transpose features (B,C,N) -> (B,N,C).
// cc is zeroed by hipMemsetAsync before this launch.
// ---------------------------------------------------------------------------
__global__ __launch_bounds__(256) void prep_kernel(const float* __restrict__ xyz,
                                                   int* __restrict__ cnt,
                                                   const float* __restrict__ f,
                                                   float* __restrict__ ft) {
    __shared__ float tile[64][65];
    if (blockIdx.x < (B * N / 256)) {
        const int g = blockIdx.x * 256 + threadIdx.x;
        const int b = g >> 14;
        const float x = xyz[g * 3 + 0], y = xyz[g * 3 + 1], z = xyz[g * 3 + 2];
        atomicAdd(&cnt[(b << 10) + cell_of(x, y, z)], 1);
    } else {
        const int bi = blockIdx.x - (B * N / 256);
        transpose_body(f, ft, (bi & 255) * 64, bi >> 8, threadIdx.x, tile);
    }
}

// Standalone transpose (fallback tiers). grid = (N/64, B), block = 256
__global__ __launch_bounds__(256) void feat_transpose_kernel(
    const float* __restrict__ f, float* __restrict__ ft) {
    __shared__ float tile[64][65];
    transpose_body(f, ft, blockIdx.x * 64, blockIdx.y, threadIdx.x, tile);
}

// ---------------------------------------------------------------------------
// Exclusive scan over 1000 cells/batch (round-0/1 harness-verified).
// grid = B, block = 1024. Writes cell_start[0..1000], re-inits cnt as cursor.
// ---------------------------------------------------------------------------
__global__ __launch_bounds__(1024) void prefix_kernel(int* __restrict__ cnt,
                                                      int* __restrict__ cs) {
    __shared__ int wsum[16];
    const int t = threadIdx.x, b = blockIdx.x;
    const int w = t >> 6, l = t & 63;
    const int v = (t < NCELL) ? cnt[(b << 10) + t] : 0;
    int inc = v;                                   // wave-inclusive scan
    #pragma unroll
    for (int off = 1; off < 64; off <<= 1) {
        const int u = __shfl_up(inc, off);
        if (l >= off) inc += u;
    }
    if (l == 63) wsum[w] = inc;
    __syncthreads();
    if (t < 16) {                                  // scan the 16 wave sums
        int s = wsum[t];
        #pragma unroll
        for (int off = 1; off < 16; off <<= 1) {
            const int u = __shfl_up(s, off, 16);
            if (t >= off) s += u;
        }
        wsum[t] = s;
    }
    __syncthreads();
    const int base = (w > 0) ? wsum[w - 1] : 0;
    const int excl = base + inc - v;               // exclusive prefix
    if (t <= NCELL) cs[b * CSTRIDE + t] = excl;    // t==1000 -> total
    if (t < NCELL)  cnt[(b << 10) + t] = excl;     // cursor init
}

// ---------------------------------------------------------------------------
// Scatter points into cell-sorted array as float4(x,y,z,bitcast(index)).
// ---------------------------------------------------------------------------
__global__ __launch_bounds__(256) void scatter_kernel(const float* __restrict__ xyz,
                                                      int* __restrict__ cursor,
                                                      float4* __restrict__ sp) {
    const int g = blockIdx.x * 256 + threadIdx.x;
    const int b = g >> 14;
    const int n = g & (N - 1);
    const float x = xyz[g * 3 + 0], y = xyz[g * 3 + 1], z = xyz[g * 3 + 2];
    const int pos = atomicAdd(&cursor[(b << 10) + cell_of(x, y, z)], 1);
    sp[(b << 14) + pos] = make_float4(x, y, z, __int_as_float(n));
}

// ---------------------------------------------------------------------------
// QG v5 = round-9 verified qg_v4 (XCD-affinity swizzle, pipelined scan,
// direct stores) at FULL occupancy: __launch_bounds__(256, 8) -> 32 waves/CU
// (VGPR cap 64; live state ~40 regs, no spill expected). qg is latency-
// bound (R8 probe: 27.3us, interior restructures all neutral) -> occupancy
// is the remaining multiplier.
// ---------------------------------------------------------------------------
__global__ __launch_bounds__(256, 8) void qg_v5_kernel(
    const float*  __restrict__ xyz,      // (B,N,3)
    const float*  __restrict__ new_xyz,  // (B,NPOINT,3)
    const float*  __restrict__ ft,       // (B,N,C)
    const int*    __restrict__ cs,       // cell_start, CSTRIDE per batch
    const float4* __restrict__ sp,       // cell-sorted points
    float* __restrict__ out_cnt,         // B*NPOINT (cnt as float)
    float* __restrict__ out_feat)        // (B,CH,NPOINT,NSAMPLE)
{
    const int w = threadIdx.x >> 6;
    const int l = threadIdx.x & 63;
    // ---- XCD-affinity swizzle (grid = 2048 blocks, 8 XCDs, 4 batches) ----
    const int bid = blockIdx.x;
    const int xcd = bid & 7;                       // dispatch round-robin slot
    const int bb  = xcd >> 1;                      // batch for this XCD pair
    const int wi  = ((bid >> 3) << 1) + (xcd & 1); // 0..511 within batch
    const int q   = (bb << 11) + (wi << 2) + w;    // bijective over 8192
    const int b   = bb;
    const int j   = q & (NPOINT - 1);

    __shared__ int cand_s[4][CAP];
    __shared__ int si_s[4][NSAMPLE];
    int* cand = cand_s[w];
    int* s_i  = si_s[w];

    const float qx = new_xyz[q * 3 + 0];
    const float qy = new_xyz[q * 3 + 1];
    const float qz = new_xyz[q * 3 + 2];

    const int cx = clamp10((int)(qx * 10.f));
    const int cy = clamp10((int)(qy * 10.f));
    const int cz = clamp10((int)(qz * 10.f));
    const int z0 = cz > 0 ? cz - 1 : 0;
    const int z1 = cz < 9 ? cz + 1 : 9;

    // prefetch all 9 run bounds in parallel (lanes 0..8), broadcast via shfl
    int sv = 0, ev = 0;
    if (l < 9) {
        const int xx = cx - 1 + l / 3;
        const int yy = cy - 1 + l % 3;
        if (xx >= 0 && xx <= 9 && yy >= 0 && yy <= 9) {
            const int cb = (xx * 10 + yy) * 10;
            sv = cs[b * CSTRIDE + cb + z0];
            ev = cs[b * CSTRIDE + cb + z1 + 1];
        }
    }

    const unsigned long long ltmask = (1ull << l) - 1ull;
    const float4* spb = sp + ((size_t)b << 14);

    // ---- 2-deep pipelined scan over the 9 runs (round-7 verified) ----
    int   rs_c = __shfl(sv, 0), re_c = __shfl(ev, 0);
    bool  a_n;
    float4 pt_n;
    {   // prefetch run 0, chunk 0 (clamped address: always a valid load)
        const int p  = rs_c + l;
        a_n = p < re_c;
        const int pc = a_n ? p : (re_c > rs_c ? re_c - 1 : 0);
        pt_n = spb[pc];
    }
    int total = 0, ncand = 0;
    for (int r = 0; r < 9; ++r) {
        const int rs = rs_c, re = re_c;
        const float4 pt = pt_n;
        const bool   act = a_n;
        if (r < 8) {        // issue NEXT run's first-chunk load immediately
            rs_c = __shfl(sv, r + 1);
            re_c = __shfl(ev, r + 1);
            const int p  = rs_c + l;
            a_n = p < re_c;
            const int pc = a_n ? p : (re_c > rs_c ? re_c - 1 : 0);
            pt_n = spb[pc];
        }
        // process current run's first chunk
        {
            const float dx = pt.x - qx, dy = pt.y - qy, dz = pt.z - qz;
            const float d2 = dx * dx + dy * dy + dz * dz;
            const bool in = act && (d2 < RADIUS2);
            const unsigned long long m = __ballot(in);
            if (in) {
                const int slot = ncand + __popcll(m & ltmask);
                if (slot < CAP) cand[slot] = __float_as_int(pt.w);
            }
            const int c = __popcll(m);
            total += c;
            ncand = ncand + c > CAP ? CAP : ncand + c;
        }
        // rare tail: current run longer than 64 points
        #pragma unroll 1
        for (int p0 = rs + 64; p0 < re; p0 += 64) {
            const int p = p0 + l;
            const bool tact = p < re;
            float4 tp = make_float4(1e9f, 1e9f, 1e9f, 0.f);
            if (tact) tp = spb[p];
            const float dx = tp.x - qx, dy = tp.y - qy, dz = tp.z - qz;
            const float d2 = dx * dx + dy * dy + dz * dz;
            const bool in = tact && (d2 < RADIUS2);
            const unsigned long long m = __ballot(in);
            if (in) {
                const int slot = ncand + __popcll(m & ltmask);
                if (slot < CAP) cand[slot] = __float_as_int(tp.w);
            }
            const int c = __popcll(m);
            total += c;
            ncand = ncand + c > CAP ? CAP : ncand + c;
        }
    }
    WAVE_FENCE();                        // cand[] appends visible wave-wide

    int cntv;
    if (total > CAP) {
        // overflow (astronomically unlikely, uniform data): ordered rescan
        const float* xb = xyz + (size_t)b * N * 3;
        int cnt2 = 0;
        for (int base = 0; base < N; base += 64) {
            const int p = base + l;
            const float dx = xb[p * 3 + 0] - qx;
            const float dy = xb[p * 3 + 1] - qy;
            const float dz = xb[p * 3 + 2] - qz;
            const float d2 = dx * dx + dy * dy + dz * dz;
            const bool in = d2 < RADIUS2;
            const unsigned long long m = __ballot(in);
            if (in) {
                const int slot = cnt2 + __popcll(m & ltmask);
                if (slot < NSAMPLE) s_i[slot] = p;
            }
            cnt2 += __popcll(m);
            if (cnt2 >= NSAMPLE) break;
        }
        cntv = cnt2 < NSAMPLE ? cnt2 : NSAMPLE;
    } else {
        // rank = #(smaller candidate indices) -> first NSAMPLE in index order
        const int K = ncand;             // == total
        for (int c = l; c < K; c += 64) {
            const int v = cand[c];
            int rnk = 0;
            for (int i = 0; i < K; ++i) rnk += (cand[i] < v) ? 1 : 0;
            if (rnk < NSAMPLE) s_i[rnk] = v;
        }
        cntv = total < NSAMPLE ? total : NSAMPLE;
    }
    WAVE_FENCE();                        // s_i writes visible

    if (l == 0) out_cnt[q] = (float)cntv;
    if (l < NSAMPLE && l >= cntv) s_i[l] = (cntv > 0) ? s_i[0] : 0;
    WAVE_FENCE();                        // fill writes visible

    // ---- xyz channels 0..2: 32 lanes, coalesced 128B per component ----
    const size_t plane = (size_t)NPOINT * NSAMPLE;          // 65536
    float* ob = out_feat + (size_t)b * CH * plane + (size_t)j * NSAMPLE;
    if (l < NSAMPLE) {
        const int i = s_i[l];
        const float* xp = xyz + ((size_t)b * N + i) * 3;
        ob[0 * plane + l] = xp[0] - qx;
        ob[1 * plane + l] = xp[1] - qy;
        ob[2 * plane + l] = xp[2] - qz;
    }

    // ---- feature channels 3..66: direct gather->store (round-6 verified) ----
    const float4* ft4 = (const float4*)ft;
    #pragma unroll
    for (int t = 0; t < 4; ++t) {
        const int k  = t * 8 + (l >> 3);
        const int c4 = l & 7;
        const int i  = s_i[k];
        const float4 va = ft4[((size_t)b * N + i) * (C / 4) + c4];
        const float4 vb = ft4[((size_t)b * N + i) * (C / 4) + 8 + c4];
        float* oa = ob + (size_t)(3 + c4 * 4) * plane + k;
        oa[0 * plane] = va.x;
        oa[1 * plane] = va.y;
        oa[2 * plane] = va.z;
        oa[3 * plane] = va.w;
        float* obp = ob + (size_t)(35 + c4 * 4) * plane + k;
        obp[0 * plane] = vb.x;
        obp[1 * plane] = vb.y;
        obp[2 * plane] = vb.z;
        obp[3 * plane] = vb.w;
    }
}

// ---------------------------------------------------------------------------
// Fallback tiers: linear-scan kernel (no grid, optional transposed features).
// ---------------------------------------------------------------------------
template <bool TRANSPOSED>
__global__ __launch_bounds__(64) void qg_wave_kernel(
    const float* __restrict__ xyz,
    const float* __restrict__ new_xyz,
    const float* __restrict__ feat,
    float* __restrict__ out_cnt,
    float* __restrict__ out_feat)
{
    const int q = blockIdx.x;
    const int b = q >> 11;
    const int j = q & (NPOINT - 1);
    const int l = threadIdx.x;

    __shared__ int   s_idx[NSAMPLE];
    __shared__ float s_tile[CH * 33];

    const float qx = new_xyz[q * 3 + 0];
    const float qy = new_xyz[q * 3 + 1];
    const float qz = new_xyz[q * 3 + 2];
    const float* xb = xyz + (size_t)b * N * 3;

    int cnt = 0;
    for (int base = 0; base < N; base += 64) {
        const int p = base + l;
        const float dx = xb[p * 3 + 0] - qx;
        const float dy = xb[p * 3 + 1] - qy;
        const float dz = xb[p * 3 + 2] - qz;
        const float d2 = dx * dx + dy * dy + dz * dz;
        const bool in = d2 < RADIUS2;
        const unsigned long long m = __ballot(in);
        if (in) {
            const int slot = cnt + __popcll(m & ((1ull << l) - 1ull));
            if (slot < NSAMPLE) s_idx[slot] = p;
        }
        cnt += __popcll(m);
        if (cnt >= NSAMPLE) break;
    }
    if (cnt > NSAMPLE) cnt = NSAMPLE;

    if (l == 0) out_cnt[q] = (float)cnt;
    __syncthreads();
    if (l < NSAMPLE && l >= cnt) s_idx[l] = (cnt > 0) ? s_idx[0] : 0;
    __syncthreads();

    #pragma unroll
    for (int p = 0; p < 8; ++p) {
        const int k  = p * 4 + (l >> 4);
        const int c4 = l & 15;
        const int i  = s_idx[k];
        if (TRANSPOSED) {
            const float4 v = ((const float4*)(feat + ((size_t)b * N + i) * C))[c4];
            const int ch = 3 + c4 * 4;
            s_tile[(ch + 0) * 33 + k] = v.x;
            s_tile[(ch + 1) * 33 + k] = v.y;
            s_tile[(ch + 2) * 33 + k] = v.z;
            s_tile[(ch + 3) * 33 + k] = v.w;
        } else {
            #pragma unroll
            for (int cc2 = 0; cc2 < 4; ++cc2) {
                const int c = c4 * 4 + cc2;
                s_tile[(3 + c) * 33 + k] = feat[((size_t)b * C + c) * N + i];
            }
        }
    }
    if (l < NSAMPLE) {
        const int i = s_idx[l];
        const float* xp = xyz + ((size_t)b * N + i) * 3;
        s_tile[0 * 33 + l] = xp[0] - qx;
        s_tile[1 * 33 + l] = xp[1] - qy;
        s_tile[2 * 33 + l] = xp[2] - qz;
    }
    __syncthreads();

    float4* of4 = (float4*)out_feat;
    for (int e4 = l; e4 < CH * 8; e4 += 64) {
        const int ch = e4 >> 3;
        const int k4 = e4 & 7;
        float4 v;
        v.x = s_tile[ch * 33 + k4 * 4 + 0];
        v.y = s_tile[ch * 33 + k4 * 4 + 1];
        v.z = s_tile[ch * 33 + k4 * 4 + 2];
        v.w = s_tile[ch * 33 + k4 * 4 + 3];
        of4[((size_t)(b * CH + ch) * NPOINT + j) * 8 + k4] = v;
    }
}

extern "C" void kernel_launch(void* const* d_in, const int* in_sizes, int n_in,
                              void* d_out, int out_size, void* d_ws, size_t ws_size,
                              hipStream_t stream) {
    const float* xyz      = (const float*)d_in[0];   // (B,N,3)
    const float* new_xyz  = (const float*)d_in[1];   // (B,NPOINT,3)
    const float* features = (const float*)d_in[2];   // (B,C,N)

    float* out_cnt  = (float*)d_out;                 // B*NPOINT
    float* out_feat = out_cnt + (size_t)B * NPOINT;  // (B,CH,NPOINT,NSAMPLE)

    char* ws = (char*)d_ws;
    const size_t ftB = (size_t)B * N * C * sizeof(float);     // 16 MB
    const size_t spB = (size_t)B * N * sizeof(float4);        // 4 MB
    const size_t csB = (size_t)B * CSTRIDE * sizeof(int);
    const size_t ccB = (size_t)B * 1024 * sizeof(int);
    const size_t need = ftB + spB + csB + ccB;

    if (ws_size >= need) {
        float*  ft = (float*)ws;
        float4* sp = (float4*)(ws + ftB);
        int*    cs = (int*)(ws + ftB + spB);
        int*    cc = (int*)(ws + ftB + spB + csB);
        hipMemsetAsync(cc, 0, ccB, stream);          // capturable async DMA fill
        prep_kernel<<<(B * N / 256) + B * (N / 64), 256, 0, stream>>>(xyz, cc,
                                                                      features, ft);
        prefix_kernel<<<B, 1024, 0, stream>>>(cc, cs);
        scatter_kernel<<<B * N / 256, 256, 0, stream>>>(xyz, cc, sp);
        qg_v5_kernel<<<B * NPOINT / 4, 256, 0, stream>>>(xyz, new_xyz, ft, cs, sp,
                                                         out_cnt, out_feat);
    } else if (ws_size >= ftB) {
        float* ft = (float*)ws;
        feat_transpose_kernel<<<dim3(N / 64, B), 256, 0, stream>>>(features, ft);
        qg_wave_kernel<true><<<B * NPOINT, 64, 0, stream>>>(xyz, new_xyz, ft,
                                                            out_cnt, out_feat);
    } else {
        qg_wave_kernel<false><<<B * NPOINT, 64, 0, stream>>>(xyz, new_xyz, features,
                                                             out_cnt, out_feat);
    }
}